// Round 9
// baseline (362.641 us; speedup 1.0000x reference)
//
#include <hip/hip_runtime.h>
#include <hip/hip_bf16.h>

#define DEVFN __device__ __forceinline__

typedef __attribute__((ext_vector_type(8))) short short8;
typedef __attribute__((ext_vector_type(4))) short short4v;
typedef __attribute__((ext_vector_type(4))) float f32x4;

#define MFMA(a,b,c) __builtin_amdgcn_mfma_f32_16x16x32_bf16((a),(b),(c),0,0,0)

DEVFN void gload_lds16(const __hip_bfloat16* g, __hip_bfloat16* l) {
  __builtin_amdgcn_global_load_lds((const __attribute__((address_space(1))) void*)g,
                                   (__attribute__((address_space(3))) void*)l, 16, 0, 0);
}

DEVFN float bf2f(__hip_bfloat16 h) { return __bfloat162float(h); }
DEVFN __hip_bfloat16 f2bf(float f) { return __float2bfloat16(f); }

DEVFN void store_out(float* p, float v) { *p = v; }
DEVFN void store_out(__hip_bfloat16* p, float v) { *p = f2bf(v); }

// ---------------------------------------------------------------------------
// K1: LayerNorm (fp32) -> xn split into bf16 hi + bf16 lo. One row per block.
// ---------------------------------------------------------------------------
__global__ __launch_bounds__(256) void ln_split_kernel(
    const float* __restrict__ x, const float* __restrict__ lw, const float* __restrict__ lb,
    __hip_bfloat16* __restrict__ xh, __hip_bfloat16* __restrict__ xl) {
  int row = blockIdx.x, t = threadIdx.x;
  float4 v = ((const float4*)(x + (size_t)row * 1024))[t];
  float s  = v.x + v.y + v.z + v.w;
  float ss = v.x*v.x + v.y*v.y + v.z*v.z + v.w*v.w;
  #pragma unroll
  for (int m = 1; m < 64; m <<= 1) { s += __shfl_xor(s, m); ss += __shfl_xor(ss, m); }
  __shared__ float red[8];
  int wv = t >> 6;
  if ((t & 63) == 0) { red[wv] = s; red[4 + wv] = ss; }
  __syncthreads();
  s  = red[0] + red[1] + red[2] + red[3];
  ss = red[4] + red[5] + red[6] + red[7];
  float mean = s * (1.f/1024.f);
  float var  = ss * (1.f/1024.f) - mean*mean;
  float inv  = rsqrtf(var + 1e-5f);
  float4 wv4 = ((const float4*)lw)[t];
  float4 bv4 = ((const float4*)lb)[t];
  float xv[4] = {v.x, v.y, v.z, v.w};
  float wa[4] = {wv4.x, wv4.y, wv4.z, wv4.w};
  float ba[4] = {bv4.x, bv4.y, bv4.z, bv4.w};
  union { short4v s4; __hip_bfloat16 h[4]; } uh, ul;
  #pragma unroll
  for (int j = 0; j < 4; ++j) {
    float val = (xv[j] - mean) * inv * wa[j] + ba[j];
    __hip_bfloat16 hi = f2bf(val);
    uh.h[j] = hi;
    ul.h[j] = f2bf(val - bf2f(hi));
  }
  ((short4v*)(xh + (size_t)row * 1024))[t] = uh.s4;
  ((short4v*)(xl + (size_t)row * 1024))[t] = ul.s4;
}

// ---------------------------------------------------------------------------
// K2: weight prep. Transpose fp32 [k][n] -> bf16 [n][k]; hi/lo split for Wq/Wk.
// ---------------------------------------------------------------------------
__global__ __launch_bounds__(256) void wprep_kernel(
    const float* __restrict__ Wq, const float* __restrict__ Wkv, const float* __restrict__ Wo,
    __hip_bfloat16* __restrict__ Wqk_h, __hip_bfloat16* __restrict__ Wqk_l,
    __hip_bfloat16* __restrict__ Wv, __hip_bfloat16* __restrict__ Wot) {
  __shared__ float tile[64][68];
  int bid = blockIdx.x, t = threadIdx.x;
  const float* src; int srcN, kt, nt, drow;
  __hip_bfloat16 *dh, *dl;
  if (bid < 256) {
    src = Wq; srcN = 1024; kt = bid >> 4; nt = bid & 15;
    dh = Wqk_h; dl = Wqk_l; drow = nt * 64;
  } else if (bid < 768) {
    int r = bid - 256; src = Wkv; srcN = 2048; kt = r >> 5; nt = r & 31;
    if (nt < 16) { dh = Wqk_h; dl = Wqk_l; drow = 1024 + nt * 64; }
    else         { dh = Wv;    dl = nullptr; drow = (nt - 16) * 64; }
  } else {
    int r = bid - 768; src = Wo; srcN = 1024; kt = r >> 4; nt = r & 15;
    dh = Wot; dl = nullptr; drow = nt * 64;
  }
  int lr = t >> 2, c = t & 3;
  const float* sp = src + (size_t)(kt*64 + lr) * srcN + nt*64 + c*16;
  float* tr = &tile[lr][c*16];
  ((float4*)tr)[0] = ((const float4*)sp)[0];
  ((float4*)tr)[1] = ((const float4*)sp)[1];
  ((float4*)tr)[2] = ((const float4*)sp)[2];
  ((float4*)tr)[3] = ((const float4*)sp)[3];
  __syncthreads();
  union { short8 s8[2]; __hip_bfloat16 h[16]; } hh, ll;
  #pragma unroll
  for (int e = 0; e < 16; ++e) {
    float wv = tile[c*16 + e][lr];
    __hip_bfloat16 hi = f2bf(wv);
    hh.h[e] = hi;
    ll.h[e] = f2bf(wv - bf2f(hi));
  }
  size_t doff = (size_t)(drow + lr) * 1024 + kt*64 + c*16;
  ((short8*)(dh + doff))[0] = hh.s8[0];
  ((short8*)(dh + doff))[1] = hh.s8[1];
  if (dl) {
    ((short8*)(dl + doff))[0] = ll.s8[0];
    ((short8*)(dl + doff))[1] = ll.s8[1];
  }
}

// ---------------------------------------------------------------------------
// K3: dual-precision GEMM (split-bf16, 3 MFMA) + fused per-head RMSNorm.
// ---------------------------------------------------------------------------
__global__ __launch_bounds__(256) void gemm_dual_kernel(
    const __hip_bfloat16* __restrict__ Ah, const __hip_bfloat16* __restrict__ Al,
    const __hip_bfloat16* __restrict__ Bh, const __hip_bfloat16* __restrict__ Bl,
    __hip_bfloat16* __restrict__ Ch, __hip_bfloat16* __restrict__ Cl,
    const float* __restrict__ qg, const float* __restrict__ kg) {
  __shared__ __align__(16) __hip_bfloat16 sAh[128*32], sAl[128*32], sBh[128*32], sBl[128*32];
  const int K = 1024, N = 2048;
  int mt = blockIdx.x, nt = blockIdx.y;
  int t = threadIdx.x, w = t >> 6, l = t & 63;
  int wr = w >> 1, wc = w & 1, lr = l & 15, lk = (l >> 4) * 8;
  f32x4 acc[4][4] = {};
  for (int k0 = 0; k0 < K; k0 += 32) {
    #pragma unroll
    for (int i = 0; i < 2; ++i) {
      int ci = i*256 + t;
      size_t ga = (size_t)(mt*128 + (ci >> 2)) * K + k0 + (ci & 3) * 8;
      size_t gb = (size_t)(nt*128 + (ci >> 2)) * K + k0 + (ci & 3) * 8;
      int ldst = (i*256 + w*64) * 8;
      gload_lds16(Ah + ga, sAh + ldst);
      gload_lds16(Al + ga, sAl + ldst);
      gload_lds16(Bh + gb, sBh + ldst);
      gload_lds16(Bl + gb, sBl + ldst);
    }
    __syncthreads();
    short8 ah[4], al[4], bh[4], bl[4];
    #pragma unroll
    for (int m = 0; m < 4; ++m) {
      int ro = (wr*64 + m*16 + lr)*32 + lk;
      ah[m] = *(const short8*)(sAh + ro);
      al[m] = *(const short8*)(sAl + ro);
    }
    #pragma unroll
    for (int n = 0; n < 4; ++n) {
      int ro = (wc*64 + n*16 + lr)*32 + lk;
      bh[n] = *(const short8*)(sBh + ro);
      bl[n] = *(const short8*)(sBl + ro);
    }
    #pragma unroll
    for (int m = 0; m < 4; ++m)
      #pragma unroll
      for (int n = 0; n < 4; ++n) {
        acc[m][n] = MFMA(ah[m], bh[n], acc[m][n]);
        acc[m][n] = MFMA(ah[m], bl[n], acc[m][n]);
        acc[m][n] = MFMA(al[m], bh[n], acc[m][n]);
      }
    __syncthreads();
  }
  int col0 = nt*128 + wc*64;
  int head = col0 >> 6;
  const float* gamma = (head < 16) ? (qg + head*64) : (kg + (head - 16)*64);
  float g[4];
  #pragma unroll
  for (int nf = 0; nf < 4; ++nf) g[nf] = gamma[nf*16 + lr];
  #pragma unroll
  for (int m = 0; m < 4; ++m) {
    #pragma unroll
    for (int r = 0; r < 4; ++r) {
      float ss2 = 0.f;
      #pragma unroll
      for (int nf = 0; nf < 4; ++nf) ss2 += acc[m][nf][r] * acc[m][nf][r];
      #pragma unroll
      for (int msk = 1; msk < 16; msk <<= 1) ss2 += __shfl_xor(ss2, msk);
      float scl = rsqrtf(ss2 * (1.f/64.f) + 1e-8f) * 8.f;
      int row = mt*128 + wr*64 + m*16 + (l >> 4)*4 + r;
      #pragma unroll
      for (int nf = 0; nf < 4; ++nf) {
        float val = acc[m][nf][r] * scl * g[nf];
        __hip_bfloat16 hi = f2bf(val);
        size_t off = (size_t)row * N + col0 + nf*16 + lr;
        Ch[off] = hi;
        Cl[off] = f2bf(val - bf2f(hi));
      }
    }
  }
}

// ---------------------------------------------------------------------------
// K4/K6: single-precision bf16 GEMM.
// ---------------------------------------------------------------------------
template <typename OUT_T>
__global__ __launch_bounds__(256) void gemm_single_kernel(
    const __hip_bfloat16* __restrict__ A, const __hip_bfloat16* __restrict__ Bt,
    OUT_T* __restrict__ C, int N) {
  __shared__ __align__(16) __hip_bfloat16 sA[128*32], sB[128*32];
  const int K = 1024;
  int mt = blockIdx.x, nt = blockIdx.y;
  int t = threadIdx.x, w = t >> 6, l = t & 63;
  int wr = w >> 1, wc = w & 1, lr = l & 15, lk = (l >> 4) * 8;
  f32x4 acc[4][4] = {};
  for (int k0 = 0; k0 < K; k0 += 32) {
    #pragma unroll
    for (int i = 0; i < 2; ++i) {
      int ci = i*256 + t;
      size_t ga = (size_t)(mt*128 + (ci >> 2)) * K + k0 + (ci & 3) * 8;
      size_t gb = (size_t)(nt*128 + (ci >> 2)) * K + k0 + (ci & 3) * 8;
      int ldst = (i*256 + w*64) * 8;
      gload_lds16(A + ga, sA + ldst);
      gload_lds16(Bt + gb, sB + ldst);
    }
    __syncthreads();
    short8 af[4], bf[4];
    #pragma unroll
    for (int m = 0; m < 4; ++m) af[m] = *(const short8*)(sA + (wr*64 + m*16 + lr)*32 + lk);
    #pragma unroll
    for (int n = 0; n < 4; ++n) bf[n] = *(const short8*)(sB + (wc*64 + n*16 + lr)*32 + lk);
    #pragma unroll
    for (int m = 0; m < 4; ++m)
      #pragma unroll
      for (int n = 0; n < 4; ++n)
        acc[m][n] = MFMA(af[m], bf[n], acc[m][n]);
    __syncthreads();
  }
  int row0 = mt*128 + wr*64, col0 = nt*128 + wc*64;
  #pragma unroll
  for (int m = 0; m < 4; ++m)
    #pragma unroll
    for (int n = 0; n < 4; ++n)
      #pragma unroll
      for (int r = 0; r < 4; ++r) {
        int row = row0 + m*16 + (l >> 4)*4 + r;
        int col = col0 + n*16 + lr;
        store_out(&C[(size_t)row * N + col], acc[m][n][r]);
      }
}

// ---------------------------------------------------------------------------
// K5a: one-shot V transpose: vbuf [b*2048+s][h*64+d] -> vT [(b*16+h)*64+d][s].
// ---------------------------------------------------------------------------
__global__ __launch_bounds__(256) void vtrans_kernel(
    const __hip_bfloat16* __restrict__ vbuf, __hip_bfloat16* __restrict__ vT) {
  __shared__ __hip_bfloat16 tile[64][72];
  int bid = blockIdx.x;                 // b*512 + h*32 + st
  int b = bid >> 9, h = (bid >> 5) & 15, st = bid & 31;
  int t = threadIdx.x, j = t >> 2, c = t & 3;
  const short8* src = (const short8*)(vbuf + (size_t)(b*2048 + st*64 + j) * 1024 + h*64 + c*16);
  *(short8*)&tile[j][c*16]     = src[0];
  *(short8*)&tile[j][c*16 + 8] = src[1];
  __syncthreads();
  int d = t >> 2, c2 = t & 3;
  union { short8 s8[2]; __hip_bfloat16 hh[16]; } o;
  #pragma unroll
  for (int e = 0; e < 16; ++e) o.hh[e] = tile[c2*16 + e][d];
  short8* dst = (short8*)(vT + (size_t)((b*16 + h)*64 + d) * 2048 + st*64 + c2*16);
  dst[0] = o.s8[0];
  dst[1] = o.s8[1];
}

// ---------------------------------------------------------------------------
// K5b: flash attention v5.1 — swapped QK^T + in-register softmax + P-via-shfl
// + V direct from L2. LDS = K hi/lo dbuf only (32KB) -> 4 blocks/CU fully
// resident (16 waves/CU), 4 independent barrier groups per CU.
//   - swapped MFMA(K,Q): lane holds S^T[kv=4*hi+r+16*nf][q=lr] in regs.
//   - P-redistribution (fixed r8 desk-check bug): dest lane (hi,lr) needs
//     quad[2kk+(hi>>1)] from src lanes 32(hi&1)+lr and +16; since __shfl
//     reads the SOURCE lane's operand, both quads must be shuffled and the
//     select done locally with the DESTINATION's hi (one shfl per quad).
//   - counted vmcnt: 4 prev-stage + 8 V + 4 next-stage => vmcnt(12).
// ---------------------------------------------------------------------------
__global__ __launch_bounds__(256) void attn_kernel(
    const __hip_bfloat16* __restrict__ qk_h, const __hip_bfloat16* __restrict__ qk_l,
    const __hip_bfloat16* __restrict__ vT, __hip_bfloat16* __restrict__ ao) {
  __shared__ __align__(16) __hip_bfloat16 sKh[2][4096], sKl[2][4096];
  int t = threadIdx.x, w = t >> 6, l = t & 63, lr = l & 15, hi = l >> 4, lk = hi * 8;
  int bh = blockIdx.x & 31, qt = blockIdx.x >> 5;
  int b = bh >> 4, h = bh & 15;
  const __hip_bfloat16* qbh = qk_h + (size_t)b * 2048 * 2048 + h * 64;
  const __hip_bfloat16* qbl = qk_l + (size_t)b * 2048 * 2048 + h * 64;
  const __hip_bfloat16* kbh = qbh + 1024;
  const __hip_bfloat16* kbl = qbl + 1024;
  const __hip_bfloat16* vtb = vT + (size_t)bh * 64 * 2048;
  int qrow = qt*64 + w*16 + lr;
  short8 qh0 = *(const short8*)(qbh + (size_t)qrow*2048 + lk);
  short8 qh1 = *(const short8*)(qbh + (size_t)qrow*2048 + 32 + lk);
  short8 ql0 = *(const short8*)(qbl + (size_t)qrow*2048 + lk);
  short8 ql1 = *(const short8*)(qbl + (size_t)qrow*2048 + 32 + lk);
  f32x4 o_acc[4] = {};
  f32x4 l_acc = {0.f, 0.f, 0.f, 0.f};
  float m_run = -1e30f;                   // running max for q = lr (scalar/lane)
  const short8 ones = {0x3F80, 0x3F80, 0x3F80, 0x3F80, 0x3F80, 0x3F80, 0x3F80, 0x3F80};

  int swl = lr & 7;                       // read-side XOR swizzle key
  int c0e = (hi ^ swl) << 3;              // swizzled chunk offset, d 0..31 slice
  int c1e = c0e ^ 32;                     // d 32..63 slice
  // staging decode: 512 chunks of 8 elems; thread t covers chunks t and 256+t
  int r0 = t >> 3, cs0 = (t & 7) ^ (r0 & 7);        // rows 0..31
  int r1 = 32 + r0, cs1 = (t & 7) ^ (r1 & 7);       // rows 32..63
  int ldb0 = (w*64) * 8, ldb1 = (256 + w*64) * 8;   // wave-uniform LDS bases

#define STAGE(B, KV) do { \
    gload_lds16(kbh + (size_t)((KV) + r0)*2048 + cs0*8, &sKh[B][0] + ldb0); \
    gload_lds16(kbh + (size_t)((KV) + r1)*2048 + cs1*8, &sKh[B][0] + ldb1); \
    gload_lds16(kbl + (size_t)((KV) + r0)*2048 + cs0*8, &sKl[B][0] + ldb0); \
    gload_lds16(kbl + (size_t)((KV) + r1)*2048 + cs1*8, &sKl[B][0] + ldb1); \
  } while (0)

  STAGE(0, 0);
  int buf = 0;
  for (int tile = 0; tile < 32; ++tile) {
    int kv0 = tile << 6;
    // V^T fragments for current tile, direct from global (L2-resident).
    short8 vreg[4][2];
    #pragma unroll
    for (int df = 0; df < 4; ++df)
      #pragma unroll
      for (int kk = 0; kk < 2; ++kk)
        vreg[df][kk] = *(const short8*)(vtb + (size_t)(df*16 + lr)*2048 + kv0 + kk*32 + lk);
    if (tile < 31) {
      STAGE(buf ^ 1, kv0 + 64);
      asm volatile("s_waitcnt vmcnt(12)" ::: "memory");  // retire prev K-stage only
    } else {
      asm volatile("s_waitcnt vmcnt(8)" ::: "memory");
    }
    __builtin_amdgcn_s_barrier();
    const __hip_bfloat16* pKh = &sKh[buf][0];
    const __hip_bfloat16* pKl = &sKl[buf][0];
    // swapped QK^T: S^T tile; lane holds S[kv=4*hi+r+16*nf][q=lr]
    f32x4 s_acc[4];
    __builtin_amdgcn_s_setprio(1);
    #pragma unroll
    for (int nf = 0; nf < 4; ++nf) {
      int rb = (nf*16 + lr) * 64;
      short8 kh0 = *(const short8*)(pKh + rb + c0e);
      short8 kh1 = *(const short8*)(pKh + rb + c1e);
      short8 kl0 = *(const short8*)(pKl + rb + c0e);
      short8 kl1 = *(const short8*)(pKl + rb + c1e);
      f32x4 sa = {};
      sa = MFMA(kh0, qh0, sa);
      sa = MFMA(kh1, qh1, sa);
      sa = MFMA(kl0, qh0, sa);
      sa = MFMA(kl1, qh1, sa);
      sa = MFMA(kh0, ql0, sa);
      sa = MFMA(kh1, ql1, sa);
      s_acc[nf] = sa;
    }
    __builtin_amdgcn_s_setprio(0);
    // in-register online softmax (defer-max THR=8)
    float mx = s_acc[0][0];
    #pragma unroll
    for (int nf = 0; nf < 4; ++nf)
      #pragma unroll
      for (int r = 0; r < 4; ++r) mx = fmaxf(mx, s_acc[nf][r]);
    mx = fmaxf(mx, __shfl_xor(mx, 16));
    mx = fmaxf(mx, __shfl_xor(mx, 32));
    if (!__all(mx <= m_run + 8.f)) {
      float mnew = fmaxf(m_run, mx);
      float corr = __expf(m_run - mnew);
      m_run = mnew;
      float corrq[4];
      #pragma unroll
      for (int r = 0; r < 4; ++r) corrq[r] = __shfl(corr, hi*4 + r);  // corr for q=4*hi+r
      #pragma unroll
      for (int r = 0; r < 4; ++r) {
        l_acc[r] *= corrq[r];
        #pragma unroll
        for (int df = 0; df < 4; ++df) o_acc[df][r] *= corrq[r];
      }
    }
    // P = exp(S - m), packed per nf into b64 quads (kv = 16*nf + 4*hi + 0..3)
    unsigned long long quad[4];
    #pragma unroll
    for (int nf = 0; nf < 4; ++nf) {
      union { unsigned long long u; unsigned short us[4]; } pk;
      #pragma unroll
      for (int r = 0; r < 4; ++r) {
        float pv = __expf(s_acc[nf][r] - m_run);
        __hip_bfloat16 pb = f2bf(pv);
        pk.us[r] = *(unsigned short*)&pb;
      }
      quad[nf] = pk.u;
    }
    // PV: A-frag = P[q=lr][kv=kk*32+hi*8+0..7], gathered from the 4 lanes
    // sharing lr. Shuffle BOTH quads, select locally with destination's hi.
    __builtin_amdgcn_s_setprio(1);
    #pragma unroll
    for (int kk = 0; kk < 2; ++kk) {
      unsigned long long q0 = quad[2*kk], q1 = quad[2*kk + 1];
      int srcA = lr + ((hi & 1) << 5);     // src lane 32*(hi&1)+lr; +16 for 2nd half
      unsigned long long a0 = __shfl(q0, srcA);
      unsigned long long a1 = __shfl(q1, srcA);
      unsigned long long b0 = __shfl(q0, srcA + 16);
      unsigned long long b1 = __shfl(q1, srcA + 16);
      union { short8 s8; unsigned long long u[2]; } pfu;
      pfu.u[0] = (hi & 2) ? a1 : a0;
      pfu.u[1] = (hi & 2) ? b1 : b0;
      short8 pf = pfu.s8;
      l_acc = MFMA(pf, ones, l_acc);
      #pragma unroll
      for (int df = 0; df < 4; ++df)
        o_acc[df] = MFMA(pf, vreg[df][kk], o_acc[df]);
    }
    __builtin_amdgcn_s_setprio(0);
    __builtin_amdgcn_s_barrier();     // all reads of buf done before next STAGE overwrites
    buf ^= 1;
  }
#undef STAGE
  size_t orow0 = (size_t)b*2048 + qt*64 + w*16 + hi*4;
  #pragma unroll
  for (int df = 0; df < 4; ++df)
    #pragma unroll
    for (int r = 0; r < 4; ++r) {
      float oval = o_acc[df][r] / l_acc[r];
      ao[(orow0 + r) * 1024 + h*64 + df*16 + lr] = f2bf(oval);
    }
}

// ---------------------------------------------------------------------------
// Workspace layout (68 MB total):
//   [ 0, 8)MB xh    -> ao after gemm_v (xh dead)
//   [ 8,16)MB xl    -> vbuf after gemm_dual (xl dead; vbuf dead after vtrans)
//   [16,32)MB qk_h
//   [32,48)MB qk_l
//   [48,52)MB Wqk_h
//   [52,56)MB Wqk_l
//   [56,58)MB Wv
//   [58,60)MB Wot
//   [60,68)MB vT
// ---------------------------------------------------------------------------
extern "C" void kernel_launch(void* const* d_in, const int* in_sizes, int n_in,
                              void* d_out, int out_size, void* d_ws, size_t ws_size,
                              hipStream_t stream) {
  const float* x   = (const float*)d_in[0];
  const float* lw  = (const float*)d_in[1];
  const float* lb  = (const float*)d_in[2];
  const float* Wq  = (const float*)d_in[3];
  const float* Wkv = (const float*)d_in[4];
  const float* qg  = (const float*)d_in[5];
  const float* kg  = (const float*)d_in[6];
  const float* Wo  = (const float*)d_in[7];
  float* out = (float*)d_out;
  char* ws = (char*)d_ws;
  const size_t MB = 1024 * 1024;
  __hip_bfloat16* xh    = (__hip_bfloat16*)(ws + 0);
  __hip_bfloat16* xl    = (__hip_bfloat16*)(ws + 8*MB);
  __hip_bfloat16* qk_h  = (__hip_bfloat16*)(ws + 16*MB);
  __hip_bfloat16* qk_l  = (__hip_bfloat16*)(ws + 32*MB);
  __hip_bfloat16* Wqk_h = (__hip_bfloat16*)(ws + 48*MB);
  __hip_bfloat16* Wqk_l = (__hip_bfloat16*)(ws + 52*MB);
  __hip_bfloat16* Wv    = (__hip_bfloat16*)(ws + 56*MB);
  __hip_bfloat16* Wot   = (__hip_bfloat16*)(ws + 58*MB);
  __hip_bfloat16* vT    = (__hip_bfloat16*)(ws + 60*MB);
  __hip_bfloat16* vbuf  = (__hip_bfloat16*)(ws + 8*MB);   // aliases xl (dead)
  __hip_bfloat16* ao    = (__hip_bfloat16*)(ws + 0);      // aliases xh (dead)

  ln_split_kernel<<<4096, 256, 0, stream>>>(x, lw, lb, xh, xl);
  wprep_kernel<<<1024, 256, 0, stream>>>(Wq, Wkv, Wo, Wqk_h, Wqk_l, Wv, Wot);
  gemm_dual_kernel<<<dim3(32, 16), 256, 0, stream>>>(xh, xl, Wqk_h, Wqk_l, qk_h, qk_l, qg, kg);
  gemm_single_kernel<__hip_bfloat16><<<dim3(32, 8), 256, 0, stream>>>(xh, Wv, vbuf, 1024);
  vtrans_kernel<<<1024, 256, 0, stream>>>(vbuf, vT);
  attn_kernel<<<1024, 256, 0, stream>>>(qk_h, qk_l, vT, ao);
  gemm_single_kernel<float><<<dim3(32, 8), 256, 0, stream>>>(ao, Wot, out, 1024);
}

// Round 10
// 318.850 us; speedup vs baseline: 1.1373x; 1.1373x over previous
//
#include <hip/hip_runtime.h>
#include <hip/hip_bf16.h>

#define DEVFN __device__ __forceinline__

typedef __attribute__((ext_vector_type(8))) short short8;
typedef __attribute__((ext_vector_type(4))) short short4v;
typedef __attribute__((ext_vector_type(4))) float f32x4;

#define MFMA(a,b,c) __builtin_amdgcn_mfma_f32_16x16x32_bf16((a),(b),(c),0,0,0)

DEVFN void gload_lds16(const __hip_bfloat16* g, __hip_bfloat16* l) {
  __builtin_amdgcn_global_load_lds((const __attribute__((address_space(1))) void*)g,
                                   (__attribute__((address_space(3))) void*)l, 16, 0, 0);
}

DEVFN float bf2f(__hip_bfloat16 h) { return __bfloat162float(h); }
DEVFN __hip_bfloat16 f2bf(float f) { return __float2bfloat16(f); }

DEVFN void store_out(float* p, float v) { *p = v; }
DEVFN void store_out(__hip_bfloat16* p, float v) { *p = f2bf(v); }

// ---------------------------------------------------------------------------
// K1: LayerNorm (fp32) -> xn split into bf16 hi + bf16 lo. One row per block.
// ---------------------------------------------------------------------------
__global__ __launch_bounds__(256) void ln_split_kernel(
    const float* __restrict__ x, const float* __restrict__ lw, const float* __restrict__ lb,
    __hip_bfloat16* __restrict__ xh, __hip_bfloat16* __restrict__ xl) {
  int row = blockIdx.x, t = threadIdx.x;
  float4 v = ((const float4*)(x + (size_t)row * 1024))[t];
  float s  = v.x + v.y + v.z + v.w;
  float ss = v.x*v.x + v.y*v.y + v.z*v.z + v.w*v.w;
  #pragma unroll
  for (int m = 1; m < 64; m <<= 1) { s += __shfl_xor(s, m); ss += __shfl_xor(ss, m); }
  __shared__ float red[8];
  int wv = t >> 6;
  if ((t & 63) == 0) { red[wv] = s; red[4 + wv] = ss; }
  __syncthreads();
  s  = red[0] + red[1] + red[2] + red[3];
  ss = red[4] + red[5] + red[6] + red[7];
  float mean = s * (1.f/1024.f);
  float var  = ss * (1.f/1024.f) - mean*mean;
  float inv  = rsqrtf(var + 1e-5f);
  float4 wv4 = ((const float4*)lw)[t];
  float4 bv4 = ((const float4*)lb)[t];
  float xv[4] = {v.x, v.y, v.z, v.w};
  float wa[4] = {wv4.x, wv4.y, wv4.z, wv4.w};
  float ba[4] = {bv4.x, bv4.y, bv4.z, bv4.w};
  union { short4v s4; __hip_bfloat16 h[4]; } uh, ul;
  #pragma unroll
  for (int j = 0; j < 4; ++j) {
    float val = (xv[j] - mean) * inv * wa[j] + ba[j];
    __hip_bfloat16 hi = f2bf(val);
    uh.h[j] = hi;
    ul.h[j] = f2bf(val - bf2f(hi));
  }
  ((short4v*)(xh + (size_t)row * 1024))[t] = uh.s4;
  ((short4v*)(xl + (size_t)row * 1024))[t] = ul.s4;
}

// ---------------------------------------------------------------------------
// K2: weight prep. Transpose fp32 [k][n] -> bf16 [n][k]; hi/lo split for Wq/Wk.
// ---------------------------------------------------------------------------
__global__ __launch_bounds__(256) void wprep_kernel(
    const float* __restrict__ Wq, const float* __restrict__ Wkv, const float* __restrict__ Wo,
    __hip_bfloat16* __restrict__ Wqk_h, __hip_bfloat16* __restrict__ Wqk_l,
    __hip_bfloat16* __restrict__ Wv, __hip_bfloat16* __restrict__ Wot) {
  __shared__ float tile[64][68];
  int bid = blockIdx.x, t = threadIdx.x;
  const float* src; int srcN, kt, nt, drow;
  __hip_bfloat16 *dh, *dl;
  if (bid < 256) {
    src = Wq; srcN = 1024; kt = bid >> 4; nt = bid & 15;
    dh = Wqk_h; dl = Wqk_l; drow = nt * 64;
  } else if (bid < 768) {
    int r = bid - 256; src = Wkv; srcN = 2048; kt = r >> 5; nt = r & 31;
    if (nt < 16) { dh = Wqk_h; dl = Wqk_l; drow = 1024 + nt * 64; }
    else         { dh = Wv;    dl = nullptr; drow = (nt - 16) * 64; }
  } else {
    int r = bid - 768; src = Wo; srcN = 1024; kt = r >> 4; nt = r & 15;
    dh = Wot; dl = nullptr; drow = nt * 64;
  }
  int lr = t >> 2, c = t & 3;
  const float* sp = src + (size_t)(kt*64 + lr) * srcN + nt*64 + c*16;
  float* tr = &tile[lr][c*16];
  ((float4*)tr)[0] = ((const float4*)sp)[0];
  ((float4*)tr)[1] = ((const float4*)sp)[1];
  ((float4*)tr)[2] = ((const float4*)sp)[2];
  ((float4*)tr)[3] = ((const float4*)sp)[3];
  __syncthreads();
  union { short8 s8[2]; __hip_bfloat16 h[16]; } hh, ll;
  #pragma unroll
  for (int e = 0; e < 16; ++e) {
    float wv = tile[c*16 + e][lr];
    __hip_bfloat16 hi = f2bf(wv);
    hh.h[e] = hi;
    ll.h[e] = f2bf(wv - bf2f(hi));
  }
  size_t doff = (size_t)(drow + lr) * 1024 + kt*64 + c*16;
  ((short8*)(dh + doff))[0] = hh.s8[0];
  ((short8*)(dh + doff))[1] = hh.s8[1];
  if (dl) {
    ((short8*)(dl + doff))[0] = ll.s8[0];
    ((short8*)(dl + doff))[1] = ll.s8[1];
  }
}

// ---------------------------------------------------------------------------
// K3: dual-precision GEMM (split-bf16, 3 MFMA) + fused per-head RMSNorm.
// ---------------------------------------------------------------------------
__global__ __launch_bounds__(256) void gemm_dual_kernel(
    const __hip_bfloat16* __restrict__ Ah, const __hip_bfloat16* __restrict__ Al,
    const __hip_bfloat16* __restrict__ Bh, const __hip_bfloat16* __restrict__ Bl,
    __hip_bfloat16* __restrict__ Ch, __hip_bfloat16* __restrict__ Cl,
    const float* __restrict__ qg, const float* __restrict__ kg) {
  __shared__ __align__(16) __hip_bfloat16 sAh[128*32], sAl[128*32], sBh[128*32], sBl[128*32];
  const int K = 1024, N = 2048;
  int mt = blockIdx.x, nt = blockIdx.y;
  int t = threadIdx.x, w = t >> 6, l = t & 63;
  int wr = w >> 1, wc = w & 1, lr = l & 15, lk = (l >> 4) * 8;
  f32x4 acc[4][4] = {};
  for (int k0 = 0; k0 < K; k0 += 32) {
    #pragma unroll
    for (int i = 0; i < 2; ++i) {
      int ci = i*256 + t;
      size_t ga = (size_t)(mt*128 + (ci >> 2)) * K + k0 + (ci & 3) * 8;
      size_t gb = (size_t)(nt*128 + (ci >> 2)) * K + k0 + (ci & 3) * 8;
      int ldst = (i*256 + w*64) * 8;
      gload_lds16(Ah + ga, sAh + ldst);
      gload_lds16(Al + ga, sAl + ldst);
      gload_lds16(Bh + gb, sBh + ldst);
      gload_lds16(Bl + gb, sBl + ldst);
    }
    __syncthreads();
    short8 ah[4], al[4], bh[4], bl[4];
    #pragma unroll
    for (int m = 0; m < 4; ++m) {
      int ro = (wr*64 + m*16 + lr)*32 + lk;
      ah[m] = *(const short8*)(sAh + ro);
      al[m] = *(const short8*)(sAl + ro);
    }
    #pragma unroll
    for (int n = 0; n < 4; ++n) {
      int ro = (wc*64 + n*16 + lr)*32 + lk;
      bh[n] = *(const short8*)(sBh + ro);
      bl[n] = *(const short8*)(sBl + ro);
    }
    #pragma unroll
    for (int m = 0; m < 4; ++m)
      #pragma unroll
      for (int n = 0; n < 4; ++n) {
        acc[m][n] = MFMA(ah[m], bh[n], acc[m][n]);
        acc[m][n] = MFMA(ah[m], bl[n], acc[m][n]);
        acc[m][n] = MFMA(al[m], bh[n], acc[m][n]);
      }
    __syncthreads();
  }
  int col0 = nt*128 + wc*64;
  int head = col0 >> 6;
  const float* gamma = (head < 16) ? (qg + head*64) : (kg + (head - 16)*64);
  float g[4];
  #pragma unroll
  for (int nf = 0; nf < 4; ++nf) g[nf] = gamma[nf*16 + lr];
  #pragma unroll
  for (int m = 0; m < 4; ++m) {
    #pragma unroll
    for (int r = 0; r < 4; ++r) {
      float ss2 = 0.f;
      #pragma unroll
      for (int nf = 0; nf < 4; ++nf) ss2 += acc[m][nf][r] * acc[m][nf][r];
      #pragma unroll
      for (int msk = 1; msk < 16; msk <<= 1) ss2 += __shfl_xor(ss2, msk);
      float scl = rsqrtf(ss2 * (1.f/64.f) + 1e-8f) * 8.f;
      int row = mt*128 + wr*64 + m*16 + (l >> 4)*4 + r;
      #pragma unroll
      for (int nf = 0; nf < 4; ++nf) {
        float val = acc[m][nf][r] * scl * g[nf];
        __hip_bfloat16 hi = f2bf(val);
        size_t off = (size_t)row * N + col0 + nf*16 + lr;
        Ch[off] = hi;
        Cl[off] = f2bf(val - bf2f(hi));
      }
    }
  }
}

// ---------------------------------------------------------------------------
// K4/K6: single-precision bf16 GEMM.
// ---------------------------------------------------------------------------
template <typename OUT_T>
__global__ __launch_bounds__(256) void gemm_single_kernel(
    const __hip_bfloat16* __restrict__ A, const __hip_bfloat16* __restrict__ Bt,
    OUT_T* __restrict__ C, int N) {
  __shared__ __align__(16) __hip_bfloat16 sA[128*32], sB[128*32];
  const int K = 1024;
  int mt = blockIdx.x, nt = blockIdx.y;
  int t = threadIdx.x, w = t >> 6, l = t & 63;
  int wr = w >> 1, wc = w & 1, lr = l & 15, lk = (l >> 4) * 8;
  f32x4 acc[4][4] = {};
  for (int k0 = 0; k0 < K; k0 += 32) {
    #pragma unroll
    for (int i = 0; i < 2; ++i) {
      int ci = i*256 + t;
      size_t ga = (size_t)(mt*128 + (ci >> 2)) * K + k0 + (ci & 3) * 8;
      size_t gb = (size_t)(nt*128 + (ci >> 2)) * K + k0 + (ci & 3) * 8;
      int ldst = (i*256 + w*64) * 8;
      gload_lds16(A + ga, sA + ldst);
      gload_lds16(Bt + gb, sB + ldst);
    }
    __syncthreads();
    short8 af[4], bf[4];
    #pragma unroll
    for (int m = 0; m < 4; ++m) af[m] = *(const short8*)(sA + (wr*64 + m*16 + lr)*32 + lk);
    #pragma unroll
    for (int n = 0; n < 4; ++n) bf[n] = *(const short8*)(sB + (wc*64 + n*16 + lr)*32 + lk);
    #pragma unroll
    for (int m = 0; m < 4; ++m)
      #pragma unroll
      for (int n = 0; n < 4; ++n)
        acc[m][n] = MFMA(af[m], bf[n], acc[m][n]);
    __syncthreads();
  }
  int row0 = mt*128 + wr*64, col0 = nt*128 + wc*64;
  #pragma unroll
  for (int m = 0; m < 4; ++m)
    #pragma unroll
    for (int n = 0; n < 4; ++n)
      #pragma unroll
      for (int r = 0; r < 4; ++r) {
        int row = row0 + m*16 + (l >> 4)*4 + r;
        int col = col0 + n*16 + lr;
        store_out(&C[(size_t)row * N + col], acc[m][n][r]);
      }
}

// ---------------------------------------------------------------------------
// K5a: one-shot V transpose: vbuf [b*2048+s][h*64+d] -> vT [(b*16+h)*64+d][s].
// ---------------------------------------------------------------------------
__global__ __launch_bounds__(256) void vtrans_kernel(
    const __hip_bfloat16* __restrict__ vbuf, __hip_bfloat16* __restrict__ vT) {
  __shared__ __hip_bfloat16 tile[64][72];
  int bid = blockIdx.x;                 // b*512 + h*32 + st
  int b = bid >> 9, h = (bid >> 5) & 15, st = bid & 31;
  int t = threadIdx.x, j = t >> 2, c = t & 3;
  const short8* src = (const short8*)(vbuf + (size_t)(b*2048 + st*64 + j) * 1024 + h*64 + c*16);
  *(short8*)&tile[j][c*16]     = src[0];
  *(short8*)&tile[j][c*16 + 8] = src[1];
  __syncthreads();
  int d = t >> 2, c2 = t & 3;
  union { short8 s8[2]; __hip_bfloat16 hh[16]; } o;
  #pragma unroll
  for (int e = 0; e < 16; ++e) o.hh[e] = tile[c2*16 + e][d];
  short8* dst = (short8*)(vT + (size_t)((b*16 + h)*64 + d) * 2048 + st*64 + c2*16);
  dst[0] = o.s8[0];
  dst[1] = o.s8[1];
}

// ---------------------------------------------------------------------------
// K5b: flash attention v6 = validated R5 structure (154us) + ONE change:
// ballot-gated lazy max. R5 ran a 4-bpermute shfl-tree row-max every tile
// only to (usually) skip the rescale (defer-max THR=8). Now: 16 in-lane
// compares + one __any; the tree+rescale runs only on the rare hit.
// corr=exp(0)=1 exactly for unaffected rows -> numerics identical.
// Everything else (2-phase dbuf, vmcnt(6), swizzle, MFMA-rowsum, setprio,
// XCD-local bh decode) is byte-identical to the R5 154us kernel.
// ---------------------------------------------------------------------------
__global__ __launch_bounds__(256) void attn_kernel(
    const __hip_bfloat16* __restrict__ qk_h, const __hip_bfloat16* __restrict__ qk_l,
    const __hip_bfloat16* __restrict__ vT, __hip_bfloat16* __restrict__ ao) {
  __shared__ __align__(16) __hip_bfloat16 sKh[2][4096], sKl[2][4096], sVt[2][4096];
  __shared__ __align__(16) __hip_bfloat16 sP[4096];
  int t = threadIdx.x, w = t >> 6, l = t & 63, lr = l & 15, hi = l >> 4, lk = hi * 8;
  int bh = blockIdx.x & 31, qt = blockIdx.x >> 5;
  int b = bh >> 4, h = bh & 15;
  const __hip_bfloat16* qbh = qk_h + (size_t)b * 2048 * 2048 + h * 64;
  const __hip_bfloat16* qbl = qk_l + (size_t)b * 2048 * 2048 + h * 64;
  const __hip_bfloat16* kbh = qbh + 1024;
  const __hip_bfloat16* kbl = qbl + 1024;
  const __hip_bfloat16* vtb = vT + (size_t)bh * 64 * 2048;
  int qrow = qt*64 + w*16 + lr;
  short8 qh0 = *(const short8*)(qbh + (size_t)qrow*2048 + lk);
  short8 qh1 = *(const short8*)(qbh + (size_t)qrow*2048 + 32 + lk);
  short8 ql0 = *(const short8*)(qbl + (size_t)qrow*2048 + lk);
  short8 ql1 = *(const short8*)(qbl + (size_t)qrow*2048 + 32 + lk);
  f32x4 o_acc[4] = {};
  f32x4 l_acc = {0.f, 0.f, 0.f, 0.f};
  float m_run[4];
  #pragma unroll
  for (int r = 0; r < 4; ++r) m_run[r] = -1e30f;
  const short8 ones = {0x3F80, 0x3F80, 0x3F80, 0x3F80, 0x3F80, 0x3F80, 0x3F80, 0x3F80};

  int swl = lr & 7;                       // read-side XOR swizzle key
  int c0e = (hi ^ swl) << 3;              // swizzled chunk offset, k 0..31 slice
  int c1e = c0e ^ 32;                     // k 32..63 slice
  // staging decode: ci in [0,512), row=ci>>3, chunk=ci&7, src chunk pre-swizzled
  int ci0 = t, ci1 = 256 + t;
  int r0 = ci0 >> 3, cs0 = (ci0 & 7) ^ (r0 & 7);
  int r1 = ci1 >> 3, cs1 = (ci1 & 7) ^ (r1 & 7);
  int ldb0 = (w*64) * 8, ldb1 = (256 + w*64) * 8;   // wave-uniform LDS bases

#define STAGE(B, KV) do { \
    gload_lds16(kbh + (size_t)((KV) + r0)*2048 + cs0*8, &sKh[B][0] + ldb0); \
    gload_lds16(kbh + (size_t)((KV) + r1)*2048 + cs1*8, &sKh[B][0] + ldb1); \
    gload_lds16(kbl + (size_t)((KV) + r0)*2048 + cs0*8, &sKl[B][0] + ldb0); \
    gload_lds16(kbl + (size_t)((KV) + r1)*2048 + cs1*8, &sKl[B][0] + ldb1); \
    gload_lds16(vtb + (size_t)r0*2048 + (KV) + cs0*8, &sVt[B][0] + ldb0); \
    gload_lds16(vtb + (size_t)r1*2048 + (KV) + cs1*8, &sVt[B][0] + ldb1); \
  } while (0)

  STAGE(0, 0);
  int buf = 0;
  for (int tile = 0; tile < 32; ++tile) {
    int kv0 = tile << 6;
    if (tile < 31) {
      STAGE(buf ^ 1, kv0 + 64);
      asm volatile("s_waitcnt vmcnt(6)" ::: "memory");  // cur tile landed; next 6 in flight
    } else {
      asm volatile("s_waitcnt vmcnt(0)" ::: "memory");
    }
    __builtin_amdgcn_s_barrier();
    const __hip_bfloat16* pKh = &sKh[buf][0];
    const __hip_bfloat16* pKl = &sKl[buf][0];
    const __hip_bfloat16* pVt = &sVt[buf][0];
    // QK^T: 16x64 logits per wave, split-bf16 3-pass
    f32x4 s_acc[4];
    __builtin_amdgcn_s_setprio(1);
    #pragma unroll
    for (int nf = 0; nf < 4; ++nf) {
      int rb = (nf*16 + lr) * 64;
      short8 kh0 = *(const short8*)(pKh + rb + c0e);
      short8 kh1 = *(const short8*)(pKh + rb + c1e);
      short8 kl0 = *(const short8*)(pKl + rb + c0e);
      short8 kl1 = *(const short8*)(pKl + rb + c1e);
      f32x4 sa = {};
      sa = MFMA(qh0, kh0, sa);
      sa = MFMA(qh1, kh1, sa);
      sa = MFMA(qh0, kl0, sa);
      sa = MFMA(qh1, kl1, sa);
      sa = MFMA(ql0, kh0, sa);
      sa = MFMA(ql1, kh1, sa);
      s_acc[nf] = sa;
    }
    __builtin_amdgcn_s_setprio(0);
    // ballot-gated lazy max: cheap detect, rare full rescale (R5 path)
    bool need = false;
    #pragma unroll
    for (int r = 0; r < 4; ++r) {
      float thr = m_run[r] + 8.f;
      #pragma unroll
      for (int nf = 0; nf < 4; ++nf) need |= (s_acc[nf][r] > thr);
    }
    if (__any(need)) {
      #pragma unroll
      for (int r = 0; r < 4; ++r) {
        float mx = fmaxf(fmaxf(s_acc[0][r], s_acc[1][r]), fmaxf(s_acc[2][r], s_acc[3][r]));
        #pragma unroll
        for (int msk = 1; msk < 16; msk <<= 1) mx = fmaxf(mx, __shfl_xor(mx, msk));
        float mnew = fmaxf(m_run[r], mx);
        float corr = __expf(m_run[r] - mnew);   // == 1.0 exactly when mx <= m_run
        m_run[r] = mnew;
        l_acc[r] *= corr;
        #pragma unroll
        for (int df = 0; df < 4; ++df) o_acc[df][r] *= corr;
      }
    }
    // P = exp(S - m_run), bf16, swizzled store to sP (conflict-free)
    #pragma unroll
    for (int r = 0; r < 4; ++r) {
      int prow = hi*4 + r;
      int pbase = (w << 10) + prow*64 + swl;
      #pragma unroll
      for (int nf = 0; nf < 4; ++nf) {
        float pv = __expf(s_acc[nf][r] - m_run[r]);
        int chunk = (nf << 1) | (lr >> 3);
        sP[pbase + ((chunk ^ (prow & 7)) << 3)] = f2bf(pv);
      }
    }
    // PV: O[q][d] += P[q][kv] * Vt[d][kv];  l[q] += P[q][kv] * 1
    __builtin_amdgcn_s_setprio(1);
    #pragma unroll
    for (int kk = 0; kk < 2; ++kk) {
      int vck = (((kk << 2) | hi) ^ swl) << 3;
      short8 pf = *(const short8*)(sP + (w << 10) + lr*64 + vck);
      l_acc = MFMA(pf, ones, l_acc);
      #pragma unroll
      for (int df = 0; df < 4; ++df) {
        short8 vf = *(const short8*)(pVt + (df*16 + lr)*64 + vck);
        o_acc[df] = MFMA(pf, vf, o_acc[df]);
      }
    }
    __builtin_amdgcn_s_setprio(0);
    __builtin_amdgcn_s_barrier();     // all reads of buf done before next STAGE overwrites
    buf ^= 1;
  }
#undef STAGE
  size_t orow0 = (size_t)b*2048 + qt*64 + w*16 + hi*4;
  #pragma unroll
  for (int df = 0; df < 4; ++df)
    #pragma unroll
    for (int r = 0; r < 4; ++r) {
      float oval = o_acc[df][r] / l_acc[r];
      ao[(orow0 + r) * 1024 + h*64 + df*16 + lr] = f2bf(oval);
    }
}

// ---------------------------------------------------------------------------
// Workspace layout (68 MB total):
//   [ 0, 8)MB xh    -> ao after gemm_v (xh dead)
//   [ 8,16)MB xl    -> vbuf after gemm_dual (xl dead; vbuf dead after vtrans)
//   [16,32)MB qk_h
//   [32,48)MB qk_l
//   [48,52)MB Wqk_h
//   [52,56)MB Wqk_l
//   [56,58)MB Wv
//   [58,60)MB Wot
//   [60,68)MB vT
// ---------------------------------------------------------------------------
extern "C" void kernel_launch(void* const* d_in, const int* in_sizes, int n_in,
                              void* d_out, int out_size, void* d_ws, size_t ws_size,
                              hipStream_t stream) {
  const float* x   = (const float*)d_in[0];
  const float* lw  = (const float*)d_in[1];
  const float* lb  = (const float*)d_in[2];
  const float* Wq  = (const float*)d_in[3];
  const float* Wkv = (const float*)d_in[4];
  const float* qg  = (const float*)d_in[5];
  const float* kg  = (const float*)d_in[6];
  const float* Wo  = (const float*)d_in[7];
  float* out = (float*)d_out;
  char* ws = (char*)d_ws;
  const size_t MB = 1024 * 1024;
  __hip_bfloat16* xh    = (__hip_bfloat16*)(ws + 0);
  __hip_bfloat16* xl    = (__hip_bfloat16*)(ws + 8*MB);
  __hip_bfloat16* qk_h  = (__hip_bfloat16*)(ws + 16*MB);
  __hip_bfloat16* qk_l  = (__hip_bfloat16*)(ws + 32*MB);
  __hip_bfloat16* Wqk_h = (__hip_bfloat16*)(ws + 48*MB);
  __hip_bfloat16* Wqk_l = (__hip_bfloat16*)(ws + 52*MB);
  __hip_bfloat16* Wv    = (__hip_bfloat16*)(ws + 56*MB);
  __hip_bfloat16* Wot   = (__hip_bfloat16*)(ws + 58*MB);
  __hip_bfloat16* vT    = (__hip_bfloat16*)(ws + 60*MB);
  __hip_bfloat16* vbuf  = (__hip_bfloat16*)(ws + 8*MB);   // aliases xl (dead)
  __hip_bfloat16* ao    = (__hip_bfloat16*)(ws + 0);      // aliases xh (dead)

  ln_split_kernel<<<4096, 256, 0, stream>>>(x, lw, lb, xh, xl);
  wprep_kernel<<<1024, 256, 0, stream>>>(Wq, Wkv, Wo, Wqk_h, Wqk_l, Wv, Wot);
  gemm_dual_kernel<<<dim3(32, 16), 256, 0, stream>>>(xh, xl, Wqk_h, Wqk_l, qk_h, qk_l, qg, kg);
  gemm_single_kernel<__hip_bfloat16><<<dim3(32, 8), 256, 0, stream>>>(xh, Wv, vbuf, 1024);
  vtrans_kernel<<<1024, 256, 0, stream>>>(vbuf, vT);
  attn_kernel<<<1024, 256, 0, stream>>>(qk_h, qk_l, vT, ao);
  gemm_single_kernel<float><<<dim3(32, 8), 256, 0, stream>>>(ao, Wot, out, 1024);
}